// Round 1
// baseline (5092.466 us; speedup 1.0000x reference)
//
#include <hip/hip_runtime.h>
#include <hip/hip_bf16.h>

#define N_    64
#define C_    64      // C_in == C_out
#define T_    300
#define V_    25
#define K_    3
#define KT_   9
#define PAD_  4

#define TT1   10                      // t per block, gcn kernel  (300/10=30)
#define TT2   10                      // t per block, tcn kernel
#define WIN_  (TT2 + 2*PAD_)          // 18 sliding window rows
#define CG_   16                      // channel group for tcn LDS staging
#define NBLK2 (N_ * (T_ / TT2))       // 1920 tcn blocks

// ---------------------------------------------------------------------------
// Kernel 1: GCN = (W x) then graph-aggregate with A, fused per (n,t) slice.
//   y2[n,c,t,w] = sum_k sum_ci W[k*64+c][ci] * (sum_v x[n,ci,t,v] * A[k,v,w])
//                 + sum_k b[k*64+c] * colsumA[k][w]
// Output y2 stored bf16 in [n][t][c][v] layout (contiguous for the TCN).
// ---------------------------------------------------------------------------
__global__ __launch_bounds__(256) void gcn_kernel(
    const float* __restrict__ x, const float* __restrict__ A,
    const float* __restrict__ Wg, const float* __restrict__ bg,
    __hip_bfloat16* __restrict__ y2)
{
    __shared__ float xs[C_ * V_];           // 1600
    __shared__ float As[K_ * V_ * V_];      // 1875
    __shared__ float xa[K_ * C_ * V_ + 8];  // 4800 + pad (harmless over-read)
    __shared__ float colA[K_ * 32];         // padded column sums of A

    const int tid = threadIdx.x;
    const int blk = blockIdx.x;
    const int n  = blk / (T_ / TT1);
    const int t0 = (blk % (T_ / TT1)) * TT1;

    // stage A once per block
    for (int i = tid; i < K_ * V_ * V_; i += 256) As[i] = A[i];
    if (tid < 8) xa[K_ * C_ * V_ + tid] = 0.0f;
    __syncthreads();
    if (tid < K_ * 32) {
        int k = tid >> 5, w = tid & 31;
        float s = 0.0f;
        if (w < V_) {
            for (int v = 0; v < V_; ++v) s += As[k * V_ * V_ + v * V_ + w];
        }
        colA[tid] = s;
    }
    __syncthreads();

    // stage-2 output mapping: thread owns channel c, v-range [w0, w0+nw)
    const int c  = tid >> 2;
    const int q  = tid & 3;
    const int w0 = q * 7;
    const int nw = (q == 3) ? 4 : 7;
    const float bc0 = bg[c], bc1 = bg[C_ + c], bc2 = bg[2 * C_ + c];

    for (int tt = 0; tt < TT1; ++tt) {
        const int t = t0 + tt;
        __syncthreads();
        // load x slice [64][25]
        for (int i = tid; i < C_ * V_; i += 256) {
            int ci = i / V_, v = i % V_;
            xs[i] = x[((size_t)(n * C_ + ci) * T_ + t) * V_ + v];
        }
        __syncthreads();
        // stage 1: xa[k][ci][w] = sum_v xs[ci][v] * As[k][v][w]
        for (int i = tid; i < K_ * C_ * V_; i += 256) {
            int k = i / (C_ * V_);
            int r = i % (C_ * V_);
            int ci = r / V_, w = r % V_;
            const float* xrow = &xs[ci * V_];
            const float* Ak   = &As[k * V_ * V_ + w];
            float acc = 0.0f;
            #pragma unroll
            for (int v = 0; v < V_; ++v) acc += xrow[v] * Ak[v * V_];
            xa[i] = acc;
        }
        __syncthreads();
        // stage 2: y2[c][w0+j] = bias + sum_k sum_ci W * xa
        float acc2[7];
        #pragma unroll
        for (int j = 0; j < 7; ++j)
            acc2[j] = bc0 * colA[w0 + j] + bc1 * colA[32 + w0 + j]
                    + bc2 * colA[64 + w0 + j];
        #pragma unroll
        for (int k = 0; k < K_; ++k) {
            const float* wrow = &Wg[(size_t)(k * C_ + c) * C_];
            const float* xak  = &xa[k * C_ * V_ + w0];
            for (int ci = 0; ci < C_; ++ci) {
                float wv = wrow[ci];
                const float* xr = &xak[ci * V_];
                #pragma unroll
                for (int j = 0; j < 7; ++j) acc2[j] += wv * xr[j];
            }
        }
        __hip_bfloat16* orow = &y2[((size_t)(n * T_ + t) * C_ + c) * V_ + w0];
        for (int j = 0; j < nw; ++j) orow[j] = __float2bfloat16(acc2[j]);
    }
}

// ---------------------------------------------------------------------------
// Kernel 2: temporal conv (9x1, pad 4) + bias, writes y3 to d_out (NCTV),
// and emits deterministic per-block per-channel partial sum / sumsq.
// ---------------------------------------------------------------------------
__global__ __launch_bounds__(256) void tcn_kernel(
    const __hip_bfloat16* __restrict__ y2,
    const float* __restrict__ Wt, const float* __restrict__ bt,
    float* __restrict__ y3, float* __restrict__ psum, float* __restrict__ psq)
{
    __shared__ float ys[WIN_ * CG_ * V_];   // 18*16*25 = 7200 floats
    __shared__ float s_sum[C_], s_sq[C_];

    const int tid = threadIdx.x;
    const int blk = blockIdx.x;
    const int n  = blk / (T_ / TT2);
    const int t0 = (blk % (T_ / TT2)) * TT2;

    const int v  = tid % V_;
    const int og = tid / V_;          // 0..10 ; og==10 (6 threads) idle
    const bool active = (og < 10);
    const int no = (og < 4) ? 7 : 6;  // o = og + 10*j

    float acc[7][TT2];
    #pragma unroll
    for (int j = 0; j < 7; ++j)
        #pragma unroll
        for (int t = 0; t < TT2; ++t) acc[j][t] = 0.0f;

    for (int cg = 0; cg < C_ / CG_; ++cg) {
        __syncthreads();
        // load window [WIN_][CG_][V_] with zero padding in t
        for (int i = tid; i < WIN_ * CG_ * V_; i += 256) {
            int twin = i / (CG_ * V_);
            int r    = i % (CG_ * V_);
            int tg   = t0 - PAD_ + twin;
            float val = 0.0f;
            if (tg >= 0 && tg < T_) {
                int ci = cg * CG_ + r / V_;
                int vv = r % V_;
                val = __bfloat162float(
                    y2[((size_t)(n * T_ + tg) * C_ + ci) * V_ + vv]);
            }
            ys[i] = val;
        }
        __syncthreads();
        if (active) {
            for (int ic = 0; ic < CG_; ++ic) {
                #pragma unroll
                for (int kt = 0; kt < KT_; ++kt) {
                    float yv[TT2];
                    #pragma unroll
                    for (int t = 0; t < TT2; ++t)
                        yv[t] = ys[(t + kt) * CG_ * V_ + ic * V_ + v];
                    #pragma unroll
                    for (int j = 0; j < 7; ++j) {
                        if (j < no) {
                            int o = og + 10 * j;
                            float wv = Wt[(size_t)(o * C_ + cg * CG_ + ic) * KT_ + kt];
                            #pragma unroll
                            for (int t = 0; t < TT2; ++t) acc[j][t] += wv * yv[t];
                        }
                    }
                }
            }
        }
    }

    __syncthreads();
    for (int i = tid; i < C_; i += 256) { s_sum[i] = 0.0f; s_sq[i] = 0.0f; }
    __syncthreads();

    if (active) {
        #pragma unroll
        for (int j = 0; j < 7; ++j) {
            if (j < no) {
                int o = og + 10 * j;
                float bias = bt[o];
                float ls = 0.0f, lq = 0.0f;
                #pragma unroll
                for (int t = 0; t < TT2; ++t) {
                    float val = acc[j][t] + bias;
                    y3[((size_t)(n * C_ + o) * T_ + (t0 + t)) * V_ + v] = val;
                    ls += val;
                    lq += val * val;
                }
                atomicAdd(&s_sum[o], ls);
                atomicAdd(&s_sq[o], lq);
            }
        }
    }
    __syncthreads();
    if (tid < C_) {
        psum[(size_t)tid * NBLK2 + blk] = s_sum[tid];
        psq [(size_t)tid * NBLK2 + blk] = s_sq [tid];
    }
}

// ---------------------------------------------------------------------------
// Kernel 3: reduce partials -> per-channel scale/shift for BN
// ---------------------------------------------------------------------------
__global__ __launch_bounds__(256) void stats_kernel(
    const float* __restrict__ psum, const float* __restrict__ psq,
    const float* __restrict__ gamma, const float* __restrict__ beta,
    float* __restrict__ sb)
{
    const int o = blockIdx.x;        // 64 blocks
    const int tid = threadIdx.x;     // 256 threads
    float s = 0.0f, q = 0.0f;
    for (int i = tid; i < NBLK2; i += 256) {
        s += psum[(size_t)o * NBLK2 + i];
        q += psq [(size_t)o * NBLK2 + i];
    }
    __shared__ float rs[256], rq[256];
    rs[tid] = s; rq[tid] = q;
    __syncthreads();
    for (int off = 128; off > 0; off >>= 1) {
        if (tid < off) { rs[tid] += rs[tid + off]; rq[tid] += rq[tid + off]; }
        __syncthreads();
    }
    if (tid == 0) {
        const float cnt = (float)(N_ * T_ * V_);
        float mean = rs[0] / cnt;
        float var  = rq[0] / cnt - mean * mean;
        float rstd = rsqrtf(var + 1e-5f);
        float sc   = gamma[o] * rstd;
        sb[o]      = sc;
        sb[C_ + o] = beta[o] - mean * sc;
    }
}

// ---------------------------------------------------------------------------
// Kernel 4: out = relu(y3*scale + shift + x)  (in-place on d_out, float4)
// ---------------------------------------------------------------------------
__global__ __launch_bounds__(256) void bn_res_relu_kernel(
    const float* __restrict__ x, const float* __restrict__ sb,
    float* __restrict__ y)
{
    const size_t total4 = (size_t)N_ * C_ * T_ * V_ / 4;  // 7,680,000
    size_t i4 = (size_t)blockIdx.x * 256 + threadIdx.x;
    if (i4 >= total4) return;
    const int c = (int)((i4 / (T_ * V_ / 4)) % C_);       // 1875 float4 per (n,c)
    const float sc = sb[c], sh = sb[C_ + c];
    float4 yv = ((const float4*)y)[i4];
    float4 xv = ((const float4*)x)[i4];
    float4 o;
    o.x = fmaxf(yv.x * sc + sh + xv.x, 0.0f);
    o.y = fmaxf(yv.y * sc + sh + xv.y, 0.0f);
    o.z = fmaxf(yv.z * sc + sh + xv.z, 0.0f);
    o.w = fmaxf(yv.w * sc + sh + xv.w, 0.0f);
    ((float4*)y)[i4] = o;
}

// ---------------------------------------------------------------------------
extern "C" void kernel_launch(void* const* d_in, const int* in_sizes, int n_in,
                              void* d_out, int out_size, void* d_ws, size_t ws_size,
                              hipStream_t stream)
{
    const float* x     = (const float*)d_in[0];
    const float* A     = (const float*)d_in[1];
    const float* wg    = (const float*)d_in[2];
    const float* bg    = (const float*)d_in[3];
    const float* wt    = (const float*)d_in[4];
    const float* bt    = (const float*)d_in[5];
    const float* gamma = (const float*)d_in[6];
    const float* beta  = (const float*)d_in[7];
    float* out = (float*)d_out;

    // workspace layout
    const size_t y2_bytes = (size_t)N_ * T_ * C_ * V_ * sizeof(__hip_bfloat16); // 61.44 MB
    __hip_bfloat16* y2 = (__hip_bfloat16*)d_ws;
    float* psum = (float*)((char*)d_ws + y2_bytes);
    float* psq  = psum + (size_t)C_ * NBLK2;
    float* sb   = psq  + (size_t)C_ * NBLK2;

    gcn_kernel<<<N_ * (T_ / TT1), 256, 0, stream>>>(x, A, wg, bg, y2);
    tcn_kernel<<<NBLK2, 256, 0, stream>>>(y2, wt, bt, out, psum, psq);
    stats_kernel<<<C_, 256, 0, stream>>>(psum, psq, gamma, beta, sb);
    const size_t total4 = (size_t)N_ * C_ * T_ * V_ / 4;
    bn_res_relu_kernel<<<(int)((total4 + 255) / 256), 256, 0, stream>>>(x, sb, out);
}

// Round 2
// 525.737 us; speedup vs baseline: 9.6863x; 9.6863x over previous
//
#include <hip/hip_runtime.h>
#include <hip/hip_bf16.h>

#define N_    64
#define C_    64      // C_in == C_out
#define T_    300
#define V_    25
#define K_    3
#define KT_   9
#define PAD_  4

typedef short bf16x8 __attribute__((ext_vector_type(8)));
typedef float f32x4  __attribute__((ext_vector_type(4)));

static __device__ __forceinline__ unsigned short f2bf(float f) {
    __hip_bfloat16 h = __float2bfloat16(f);
    return __builtin_bit_cast(unsigned short, h);
}

// ---------------------------------------------------------------------------
// prep: weight tables (bf16, MFMA-friendly layouts) + fused GCN bias table.
//   Wtb [kt][o][c]      = Wt[o][c][kt]              (9*64*64)
//   Wgbt[o][k*64+ci]    = Wg[k*64+o][ci]            (64*192)
//   bias2[c][w]         = sum_k bg[k*64+c] * sum_v A[k,v,w]   (64*25, f32)
// ---------------------------------------------------------------------------
__global__ __launch_bounds__(256) void prep_kernel(
    const float* __restrict__ Wt, const float* __restrict__ Wg,
    const float* __restrict__ bg, const float* __restrict__ A,
    unsigned short* __restrict__ Wtb, unsigned short* __restrict__ Wgbt,
    float* __restrict__ bias2)
{
    int i = blockIdx.x * 256 + threadIdx.x;
    if (i < 9*64*64) {
        int kt = i >> 12, r = i & 4095, o = r >> 6, c = r & 63;
        Wtb[i] = f2bf(Wt[(size_t)(o*64 + c)*9 + kt]);
    }
    int j = i - 9*64*64;
    if (j >= 0 && j < 64*192) {
        int o = j / 192, kc = j - 192*(j/192);
        int k = kc >> 6, ci = kc & 63;
        Wgbt[j] = f2bf(Wg[(size_t)(k*64 + o)*64 + ci]);
    }
    int m = i - 9*64*64 - 64*192;
    if (m >= 0 && m < 64*25) {
        int c = m / 25, w = m - 25*(m/25);
        float s = 0.f;
        for (int k = 0; k < 3; ++k) {
            float col = 0.f;
            for (int v = 0; v < 25; ++v) col += A[k*625 + v*25 + w];
            s += bg[k*64 + c] * col;
        }
        bias2[m] = s;
    }
}

// ---------------------------------------------------------------------------
// GCN: per (n, 6-t tile).  stage x -> vector stage-1 (x @ A_k, A col in regs)
// -> swizzled bf16 xa slab [col][192] -> MFMA stage-2 (M=64,N=150,K=192)
// -> bias -> LDS bounce -> contiguous y2 store, layout [(n,t,v)][c] bf16.
// ---------------------------------------------------------------------------
#define GTT    6
#define GCOLS  (GTT*25)        // 150
#define GTILES (T_/GTT)        // 50
#define XAPAD  160             // padded col count (stage-2 reads cols 150..159)

__global__ __launch_bounds__(256, 1) void gcn_kernel(
    const float* __restrict__ x, const float* __restrict__ A,
    const unsigned short* __restrict__ Wgbt, const float* __restrict__ bias2,
    unsigned short* __restrict__ y2)
{
    __shared__ float xs[C_*GTT*28];            // 43008 B; reused as y2 bounce
    __shared__ unsigned short xa[XAPAD*192];   // 61440 B, swizzled [col][kc]
    __shared__ float b2s[C_*V_];               // 6400 B

    const int tid = threadIdx.x;
    const int n  = blockIdx.x / GTILES;
    const int t0 = (blockIdx.x % GTILES) * GTT;

    // stage bias table + x slab (pad v=25..27 with zeros; disjoint writes)
    for (int i = tid; i < C_*V_; i += 256) b2s[i] = bias2[i];
    for (int i = tid; i < C_*GTT*3; i += 256) {
        int ci = i / (GTT*3), r = i - (GTT*3)*(i/(GTT*3));
        xs[ci*(GTT*28) + (r/3)*28 + 25 + (r - 3*(r/3))] = 0.f;
    }
    for (int i = tid; i < C_*GCOLS; i += 256) {
        int ci = i / GCOLS, col = i - GCOLS*(i/GCOLS);
        int tl = col / 25, v = col - 25*tl;
        xs[ci*(GTT*28) + tl*28 + v] =
            x[(size_t)(n*C_ + ci)*(T_*V_) + t0*25 + col];
    }
    __syncthreads();

    // ---- stage 1: xa[col][k*64+ci] = sum_v x[ci][tl][v] * A[k][v][w]
    {
        const int kw = tid % 75;
        const int g  = tid / 75;               // tid >= 225 idle
        if (g < 3) {
            const int k = kw / 25, w = kw - 25*(kw/25);
            const int ci0 = g*22, cic = (g == 2) ? 20 : 22;
            float areg[25];
            #pragma unroll
            for (int v = 0; v < 25; ++v) areg[v] = A[k*625 + v*25 + w];
            for (int ci = ci0; ci < ci0 + cic; ++ci) {
                #pragma unroll
                for (int tl = 0; tl < GTT; ++tl) {
                    const float* xr = &xs[ci*(GTT*28) + tl*28];
                    float acc = 0.f;
                    #pragma unroll
                    for (int e = 0; e < 6; ++e) {
                        float4 xv = *(const float4*)&xr[e*4];
                        acc += xv.x*areg[e*4]   + xv.y*areg[e*4+1]
                             + xv.z*areg[e*4+2] + xv.w*areg[e*4+3];
                    }
                    acc += xr[24]*areg[24];
                    int col = tl*25 + w;
                    int byte = (col*384 + (k*64 + ci)*2) ^ ((col & 7) << 4);
                    *(unsigned short*)((char*)xa + byte) = f2bf(acc);
                }
            }
        }
    }
    __syncthreads();

    // ---- stage 2: MFMA  D[o][col] = sum_kc Wgbt[o][kc] * xa[col][kc]
    const int lane = tid & 63, wave = tid >> 6;
    const int l15 = lane & 15, lq = lane >> 4;

    f32x4 acc[4][3] = {};
    #pragma unroll
    for (int cb = 0; cb < 6; ++cb) {
        bf16x8 a[4];
        #pragma unroll
        for (int mt = 0; mt < 4; ++mt)
            a[mt] = *(const bf16x8*)(Wgbt + (mt*16 + l15)*192 + cb*32 + lq*8);
        #pragma unroll
        for (int j = 0; j < 3; ++j) {
            int nf = wave*3 + j;
            if (nf < 10) {
                int col = nf*16 + l15;
                int byte = (col*384 + cb*64 + lq*16) ^ ((col & 7) << 4);
                bf16x8 b = *(const bf16x8*)((const char*)xa + byte);
                #pragma unroll
                for (int mt = 0; mt < 4; ++mt)
                    acc[mt][j] = __builtin_amdgcn_mfma_f32_16x16x32_bf16(
                        a[mt], b, acc[mt][j], 0, 0, 0);
            }
        }
    }

    __syncthreads();   // stage-1 xs readers done; xs becomes bounce buffer
    unsigned short* bb = (unsigned short*)xs;  // [col][64] bf16, swizzled
    #pragma unroll
    for (int mt = 0; mt < 4; ++mt) {
        #pragma unroll
        for (int j = 0; j < 3; ++j) {
            int nf = wave*3 + j;
            if (nf < 10) {
                int col = nf*16 + l15;
                if (col < GCOLS) {
                    int w = col % 25;
                    #pragma unroll
                    for (int p = 0; p < 2; ++p) {
                        int o0 = mt*16 + lq*4 + p*2;
                        float v0 = acc[mt][j][2*p]   + b2s[o0*25 + w];
                        float v1 = acc[mt][j][2*p+1] + b2s[(o0+1)*25 + w];
                        unsigned int bits = (unsigned int)f2bf(v0)
                                          | ((unsigned int)f2bf(v1) << 16);
                        int byte = (col*128 + o0*2) ^ ((col & 7) << 4);
                        *(unsigned int*)((char*)bb + byte) = bits;
                    }
                }
            }
        }
    }
    __syncthreads();
    // bounce -> global: 150 cols * 128 B contiguous
    const size_t gbase = ((size_t)n*T_ + t0) * V_ * C_;   // element offset
    for (int i = tid; i < GCOLS*8; i += 256) {
        int col = i >> 3, ck = i & 7;
        int byte = (col*128 + ck*16) ^ ((col & 7) << 4);
        float4 d = *(const float4*)((const char*)bb + byte);
        *(float4*)((char*)y2 + (gbase + (size_t)col*64 + ck*8)*2) = d;
    }
}

// ---------------------------------------------------------------------------
// TCN: per (n, 20-t tile).  Stage y2 slab [712 cols][64 c] bf16 (swizzled,
// zero-padded t), then 9 conv taps = column-shifted MFMA reads. M=64, N=500,
// K=576.  Fused bias + per-block BN partial sums.
// ---------------------------------------------------------------------------
#define TTT    20
#define TCOLS  (TTT*25)         // 500
#define SLABC  712              // 500 + 200 halo + 12 pad for nf overrun
#define TTILES (T_/TTT)         // 15
#define NBLK   (N_*TTILES)      // 960

#define LOADA(dst, s) { int kt_ = (s) >> 1, cb_ = (s) & 1;                    \
    _Pragma("unroll")                                                          \
    for (int mt = 0; mt < 4; ++mt)                                             \
        dst[mt] = *(const bf16x8*)(Wtb + (kt_*64 + mt*16 + l15)*64             \
                                   + cb_*32 + lq*8); }

#define COMPUTE(a_, s) { int kt_ = (s) >> 1, cb_ = (s) & 1;                   \
    _Pragma("unroll")                                                          \
    for (int nf = 0; nf < 8; ++nf) {                                           \
        int col = colw + nf*16 + l15 + kt_*25;                                 \
        int byte = (col*128 + cb_*64 + lq*16) ^ ((col & 7) << 4);              \
        bf16x8 b = *(const bf16x8*)((const char*)slab + byte);                 \
        _Pragma("unroll")                                                      \
        for (int mt = 0; mt < 4; ++mt)                                         \
            acc[mt][nf] = __builtin_amdgcn_mfma_f32_16x16x32_bf16(             \
                a_[mt], b, acc[mt][nf], 0, 0, 0); } }

__global__ __launch_bounds__(256, 1) void tcn_kernel(
    const unsigned short* __restrict__ y2, const unsigned short* __restrict__ Wtb,
    const float* __restrict__ bt,
    float* __restrict__ y3, float* __restrict__ psum, float* __restrict__ psq)
{
    __shared__ unsigned short slab[SLABC*64];   // 91136 B
    __shared__ float s_sum[64], s_sq[64];

    const int tid = threadIdx.x;
    const int n  = blockIdx.x / TTILES;
    const int t0 = (blockIdx.x % TTILES) * TTT;

    if (tid < 64) { s_sum[tid] = 0.f; s_sq[tid] = 0.f; }

    for (int i = tid; i < SLABC*8; i += 256) {
        int col = i >> 3, ck = i & 7;
        int tl = col / 25, v = col - 25*tl;
        int t = t0 - PAD_ + tl;
        float4 val = {0.f, 0.f, 0.f, 0.f};
        if (t >= 0 && t < T_)
            val = *(const float4*)((const char*)y2
                    + (((size_t)(n*T_ + t)*V_ + v)*64 + ck*8)*2);
        int byte = (col*128 + ck*16) ^ ((col & 7) << 4);
        *(float4*)((char*)slab + byte) = val;
    }
    __syncthreads();

    const int lane = tid & 63, wave = tid >> 6;
    const int l15 = lane & 15, lq = lane >> 4;
    const int colw = wave * 128;

    f32x4 acc[4][8] = {};
    bf16x8 aA[4], aB[4];
    LOADA(aA, 0);
    #pragma unroll 1
    for (int s = 0; s < 18; s += 2) {        // (kt, cb) flattened, pipelined
        LOADA(aB, s + 1);
        COMPUTE(aA, s);
        if (s + 2 < 18) LOADA(aA, s + 2);
        COMPUTE(aB, s + 1);
    }

    // epilogue: bias + store + per-block BN partials
    #pragma unroll
    for (int mt = 0; mt < 4; ++mt) {
        #pragma unroll
        for (int r = 0; r < 4; ++r) {
            const int o = mt*16 + lq*4 + r;
            const float bias = bt[o];
            float ls = 0.f, lsq = 0.f;
            #pragma unroll
            for (int nf = 0; nf < 8; ++nf) {
                int ocol = colw + nf*16 + l15;
                if (ocol < TCOLS) {
                    int tl = ocol / 25, v = ocol - 25*tl;
                    float val = acc[mt][nf][r] + bias;
                    y3[((size_t)(n*C_ + o)*T_ + t0 + tl)*V_ + v] = val;
                    ls += val; lsq += val*val;
                }
            }
            atomicAdd(&s_sum[o], ls);
            atomicAdd(&s_sq[o], lsq);
        }
    }
    __syncthreads();
    if (tid < 64) {
        psum[(size_t)tid*NBLK + blockIdx.x] = s_sum[tid];
        psq [(size_t)tid*NBLK + blockIdx.x] = s_sq [tid];
    }
}

// ---------------------------------------------------------------------------
// stats: reduce partials -> per-channel scale/shift
// ---------------------------------------------------------------------------
__global__ __launch_bounds__(256) void stats_kernel(
    const float* __restrict__ psum, const float* __restrict__ psq,
    const float* __restrict__ gamma, const float* __restrict__ beta,
    float* __restrict__ sb)
{
    const int o = blockIdx.x;
    const int tid = threadIdx.x;
    float s = 0.f, q = 0.f;
    for (int i = tid; i < NBLK; i += 256) {
        s += psum[(size_t)o*NBLK + i];
        q += psq [(size_t)o*NBLK + i];
    }
    __shared__ float rs[256], rq[256];
    rs[tid] = s; rq[tid] = q;
    __syncthreads();
    for (int off = 128; off > 0; off >>= 1) {
        if (tid < off) { rs[tid] += rs[tid + off]; rq[tid] += rq[tid + off]; }
        __syncthreads();
    }
    if (tid == 0) {
        const float cnt = (float)(N_ * T_ * V_);
        float mean = rs[0] / cnt;
        float var  = rq[0] / cnt - mean * mean;
        float rstd = rsqrtf(var + 1e-5f);
        float sc   = gamma[o] * rstd;
        sb[o]      = sc;
        sb[C_ + o] = beta[o] - mean * sc;
    }
}

// ---------------------------------------------------------------------------
// BN + residual + ReLU, in place on d_out
// ---------------------------------------------------------------------------
__global__ __launch_bounds__(256) void bn_res_relu_kernel(
    const float* __restrict__ x, const float* __restrict__ sb,
    float* __restrict__ y)
{
    const size_t total4 = (size_t)N_ * C_ * T_ * V_ / 4;  // 7,680,000
    size_t i4 = (size_t)blockIdx.x * 256 + threadIdx.x;
    if (i4 >= total4) return;
    const int c = (int)((i4 / (T_ * V_ / 4)) % C_);
    const float sc = sb[c], sh = sb[C_ + c];
    float4 yv = ((const float4*)y)[i4];
    float4 xv = ((const float4*)x)[i4];
    float4 o;
    o.x = fmaxf(yv.x * sc + sh + xv.x, 0.0f);
    o.y = fmaxf(yv.y * sc + sh + xv.y, 0.0f);
    o.z = fmaxf(yv.z * sc + sh + xv.z, 0.0f);
    o.w = fmaxf(yv.w * sc + sh + xv.w, 0.0f);
    ((float4*)y)[i4] = o;
}

// ---------------------------------------------------------------------------
extern "C" void kernel_launch(void* const* d_in, const int* in_sizes, int n_in,
                              void* d_out, int out_size, void* d_ws, size_t ws_size,
                              hipStream_t stream)
{
    const float* x     = (const float*)d_in[0];
    const float* A     = (const float*)d_in[1];
    const float* wg    = (const float*)d_in[2];
    const float* bg    = (const float*)d_in[3];
    const float* wt    = (const float*)d_in[4];
    const float* bt    = (const float*)d_in[5];
    const float* gamma = (const float*)d_in[6];
    const float* beta  = (const float*)d_in[7];
    float* out = (float*)d_out;

    char* wsb = (char*)d_ws;
    // y2: [(n,t,v)][c] bf16, 30.72M elems = 61,440,000 B
    unsigned short* y2   = (unsigned short*)wsb;
    float* psum          = (float*)(wsb + 61440000);
    float* psq           = (float*)(wsb + 61440000 + 245760);
    float* sb            = (float*)(wsb + 61440000 + 2*245760);
    unsigned short* Wtb  = (unsigned short*)(wsb + 61440000 + 2*245760 + 512);
    unsigned short* Wgbt = (unsigned short*)(wsb + 61440000 + 2*245760 + 512 + 73728);
    float* bias2         = (float*)(wsb + 61440000 + 2*245760 + 512 + 73728 + 24576);

    prep_kernel<<<199, 256, 0, stream>>>(wt, wg, bg, A, Wtb, Wgbt, bias2);
    gcn_kernel<<<N_*GTILES, 256, 0, stream>>>(x, A, Wgbt, bias2, y2);
    tcn_kernel<<<NBLK, 256, 0, stream>>>(y2, Wtb, bt, out, psum, psq);
    stats_kernel<<<C_, 256, 0, stream>>>(psum, psq, gamma, beta, sb);
    const size_t total4 = (size_t)N_ * C_ * T_ * V_ / 4;
    bn_res_relu_kernel<<<(int)((total4 + 255) / 256), 256, 0, stream>>>(x, sb, out);
}

// Round 3
// 405.039 us; speedup vs baseline: 12.5728x; 1.2980x over previous
//
#include <hip/hip_runtime.h>
#include <hip/hip_bf16.h>

#define N_    64
#define C_    64      // C_in == C_out
#define T_    300
#define V_    25
#define K_    3
#define KT_   9
#define PAD_  4

typedef short bf16x8 __attribute__((ext_vector_type(8)));
typedef float f32x4  __attribute__((ext_vector_type(4)));

static __device__ __forceinline__ unsigned short f2bf(float f) {
    __hip_bfloat16 h = __float2bfloat16(f);
    return __builtin_bit_cast(unsigned short, h);
}
static __device__ __forceinline__ unsigned int pk2(float a, float b) {
    return (unsigned int)f2bf(a) | ((unsigned int)f2bf(b) << 16);
}

// ---------------------------------------------------------------------------
// prep: weight tables (bf16, MFMA-friendly layouts) + fused GCN bias table.
//   Wtb [kt][o][c]    = Wt[o][c][kt]                      (9*64*64)
//   Wgbt[o][k*64+ci]  = Wg[k*64+o][ci]                    (64*192)
//   bias2[c][w]       = sum_k bg[k*64+c]*sum_v A[k,v,w]   (64*25 f32)
//   Abt [k][w:32][v:40] = A[k,v,w]  (zero-padded)         (3*32*40)
// ---------------------------------------------------------------------------
__global__ __launch_bounds__(256) void prep_kernel(
    const float* __restrict__ Wt, const float* __restrict__ Wg,
    const float* __restrict__ bg, const float* __restrict__ A,
    unsigned short* __restrict__ Wtb, unsigned short* __restrict__ Wgbt,
    float* __restrict__ bias2, unsigned short* __restrict__ Abt)
{
    int i = blockIdx.x * 256 + threadIdx.x;
    if (i < 9*64*64) {
        int kt = i >> 12, r = i & 4095, o = r >> 6, c = r & 63;
        Wtb[i] = f2bf(Wt[(size_t)(o*64 + c)*9 + kt]);
    }
    int j = i - 9*64*64;
    if (j >= 0 && j < 64*192) {
        int o = j / 192, kc = j - 192*(j/192);
        int k = kc >> 6, ci = kc & 63;
        Wgbt[j] = f2bf(Wg[(size_t)(k*64 + o)*64 + ci]);
    }
    int m = j - 64*192;
    if (m >= 0 && m < 64*25) {
        int c = m / 25, w = m - 25*(m/25);
        float s = 0.f;
        for (int k = 0; k < 3; ++k) {
            float col = 0.f;
            for (int v = 0; v < 25; ++v) col += A[k*625 + v*25 + w];
            s += bg[k*64 + c] * col;
        }
        bias2[m] = s;
    }
    int p = m - 64*25;
    if (p >= 0 && p < 3*32*40) {
        int k = p / 1280, r = p - 1280*k, w = r / 40, v = r - 40*(r/40);
        float val = (w < 25 && v < 25) ? A[k*625 + v*25 + w] : 0.f;
        Abt[p] = f2bf(val);
    }
}

// ---------------------------------------------------------------------------
// GCN (all-MFMA): per (n, 2-t tile).
//  stage-1: xa[(tl,w)][k*64+ci] = sum_v x[(tl,ci)][v] * A_k[v][w]
//           MFMA M=128 (tl,ci), K=32 (v pad), N=32 (w pad), per k.
//  stage-2: y2[o][(tl,w)] = bias2[o][w] + sum_kc Wgbt[o][kc]*xa[col][kc]
//           MFMA M=64, K=192, N=64 (50 valid cols).
//  LDS rows odd multiples of 16B (80B / 400B) -> bank-start spread.
// ---------------------------------------------------------------------------
#define GTT    2
#define GTILES (T_/GTT)     // 150
#define GCVAL  (GTT*V_)     // 50 valid cols
#define XROWS  (GTT*C_)     // 128

__global__ __launch_bounds__(256, 3) void gcn_kernel(
    const float* __restrict__ x,
    const unsigned short* __restrict__ Wgbt,
    const unsigned short* __restrict__ Abt,
    const float* __restrict__ bias2,
    unsigned short* __restrict__ y2)
{
    __shared__ unsigned short xslab[XROWS*40];  // [tl*64+ci][40]  80B rows
    __shared__ unsigned short Ab[3*32*40];      // [k][w][40]      80B rows
    __shared__ unsigned short xa[64*200];       // [col][200]     400B rows

    const int tid  = threadIdx.x;
    const int n    = blockIdx.x / GTILES;
    const int t0   = (blockIdx.x % GTILES) * GTT;
    const int lane = tid & 63, wave = tid >> 6;
    const int l15  = lane & 15, lq = lane >> 4;

    // preload stage-2 weight A-frags (L2-hot, 24 x b128)
    bf16x8 wfrag[4][6];
    #pragma unroll
    for (int mt = 0; mt < 4; ++mt)
        #pragma unroll
        for (int cb = 0; cb < 6; ++cb)
            wfrag[mt][cb] = *(const bf16x8*)(Wgbt + (mt*16 + l15)*192 + cb*32 + lq*8);

    // stage Ab (straight u32 copy)
    for (int i = tid; i < 1920; i += 256)
        ((unsigned int*)Ab)[i] = ((const unsigned int*)Abt)[i];
    // zero x-slab elems 26..39 (u32 slots 13..19 per row) -- disjoint from fill
    for (int i = tid; i < XROWS*7; i += 256) {
        int row = i / 7, s = i - 7*row;
        ((unsigned int*)xslab)[row*20 + 13 + s] = 0u;
    }
    // fill x-slab elems 0..25 as packed pairs (elem 25 forced 0)
    for (int i = tid; i < XROWS*13; i += 256) {
        int row = i / 13, s = i - 13*row;
        int ci = row & 63, tl = row >> 6;
        const float* xr = x + ((size_t)(n*C_ + ci)*T_ + t0 + tl)*V_;
        float f0 = xr[2*s];
        float f1 = (2*s + 1 < 25) ? xr[2*s + 1] : 0.f;
        ((unsigned int*)xslab)[row*20 + s] = pk2(f0, f1);
    }
    __syncthreads();

    // ---- stage 1: MFMA x-slab @ A_k^T -> xa
    {
        const int mt0 = wave*2;
        bf16x8 xf0 = *(const bf16x8*)(xslab + (mt0*16 + l15)*40 + lq*8);
        bf16x8 xf1 = *(const bf16x8*)(xslab + ((mt0+1)*16 + l15)*40 + lq*8);
        #pragma unroll
        for (int k = 0; k < 3; ++k) {
            #pragma unroll
            for (int nt = 0; nt < 2; ++nt) {
                bf16x8 bf = *(const bf16x8*)(Ab + (k*32 + nt*16 + l15)*40 + lq*8);
                f32x4 d0 = {}, d1 = {};
                d0 = __builtin_amdgcn_mfma_f32_16x16x32_bf16(xf0, bf, d0, 0, 0, 0);
                d1 = __builtin_amdgcn_mfma_f32_16x16x32_bf16(xf1, bf, d1, 0, 0, 0);
                const int w = nt*16 + l15;
                if (w < 25) {
                    {
                        const int mt = mt0;
                        const int tl = mt >> 2;
                        const int ci0 = (mt & 3)*16 + lq*4;
                        const int col = tl*25 + w;
                        unsigned long long pv =
                              (unsigned long long)pk2(d0[0], d0[1])
                            | ((unsigned long long)pk2(d0[2], d0[3]) << 32);
                        *(unsigned long long*)((char*)xa + col*400 + (k*64 + ci0)*2) = pv;
                    }
                    {
                        const int mt = mt0 + 1;
                        const int tl = mt >> 2;
                        const int ci0 = (mt & 3)*16 + lq*4;
                        const int col = tl*25 + w;
                        unsigned long long pv =
                              (unsigned long long)pk2(d1[0], d1[1])
                            | ((unsigned long long)pk2(d1[2], d1[3]) << 32);
                        *(unsigned long long*)((char*)xa + col*400 + (k*64 + ci0)*2) = pv;
                    }
                }
            }
        }
    }
    __syncthreads();

    // ---- stage 2: MFMA Wgbt @ xa -> y2  (wave owns n-tile = wave)
    f32x4 acc[4] = {};
    const int col = wave*16 + l15;
    #pragma unroll
    for (int cb = 0; cb < 6; ++cb) {
        bf16x8 b = *(const bf16x8*)((const char*)xa + col*400 + cb*64 + lq*16);
        #pragma unroll
        for (int mt = 0; mt < 4; ++mt)
            acc[mt] = __builtin_amdgcn_mfma_f32_16x16x32_bf16(
                wfrag[mt][cb], b, acc[mt], 0, 0, 0);
    }
    if (col < GCVAL) {
        const int tl = col / 25, w = col - 25*(col/25);
        const size_t gcol = ((size_t)n*T_ + t0 + tl)*V_ + w;
        #pragma unroll
        for (int mt = 0; mt < 4; ++mt) {
            const int o0 = mt*16 + lq*4;
            float v0 = acc[mt][0] + bias2[(o0+0)*25 + w];
            float v1 = acc[mt][1] + bias2[(o0+1)*25 + w];
            float v2 = acc[mt][2] + bias2[(o0+2)*25 + w];
            float v3 = acc[mt][3] + bias2[(o0+3)*25 + w];
            unsigned long long pv = (unsigned long long)pk2(v0, v1)
                                  | ((unsigned long long)pk2(v2, v3) << 32);
            *(unsigned long long*)((char*)y2 + (gcol*64 + o0)*2) = pv;
        }
    }
}

// ---------------------------------------------------------------------------
// TCN: per (n, 20-t tile).  Stage y2 slab [712 cols][64 c] bf16 (swizzled,
// zero-padded t), then 9 conv taps = column-shifted MFMA reads. M=64, N=500,
// K=576.  Fused bias + per-block BN partial sums.
// ---------------------------------------------------------------------------
#define TTT    20
#define TCOLS  (TTT*25)         // 500
#define SLABC  712              // 500 + 200 halo + 12 pad for nf overrun
#define TTILES (T_/TTT)         // 15
#define NBLK   (N_*TTILES)      // 960

#define LOADA(dst, s) { int kt_ = (s) >> 1, cb_ = (s) & 1;                    \
    _Pragma("unroll")                                                          \
    for (int mt = 0; mt < 4; ++mt)                                             \
        dst[mt] = *(const bf16x8*)(Wtb + (kt_*64 + mt*16 + l15)*64             \
                                   + cb_*32 + lq*8); }

#define COMPUTE(a_, s) { int kt_ = (s) >> 1, cb_ = (s) & 1;                   \
    _Pragma("unroll")                                                          \
    for (int nf = 0; nf < 8; ++nf) {                                           \
        int col = colw + nf*16 + l15 + kt_*25;                                 \
        int byte = (col*128 + cb_*64 + lq*16) ^ ((col & 7) << 4);              \
        bf16x8 b = *(const bf16x8*)((const char*)slab + byte);                 \
        _Pragma("unroll")                                                      \
        for (int mt = 0; mt < 4; ++mt)                                         \
            acc[mt][nf] = __builtin_amdgcn_mfma_f32_16x16x32_bf16(             \
                a_[mt], b, acc[mt][nf], 0, 0, 0); } }

__global__ __launch_bounds__(256, 1) void tcn_kernel(
    const unsigned short* __restrict__ y2, const unsigned short* __restrict__ Wtb,
    const float* __restrict__ bt,
    float* __restrict__ y3, float* __restrict__ psum, float* __restrict__ psq)
{
    __shared__ unsigned short slab[SLABC*64];   // 91136 B
    __shared__ float s_sum[64], s_sq[64];

    const int tid = threadIdx.x;
    const int n  = blockIdx.x / TTILES;
    const int t0 = (blockIdx.x % TTILES) * TTT;

    if (tid < 64) { s_sum[tid] = 0.f; s_sq[tid] = 0.f; }

    for (int i = tid; i < SLABC*8; i += 256) {
        int col = i >> 3, ck = i & 7;
        int tl = col / 25, v = col - 25*tl;
        int t = t0 - PAD_ + tl;
        float4 val = {0.f, 0.f, 0.f, 0.f};
        if (t >= 0 && t < T_)
            val = *(const float4*)((const char*)y2
                    + (((size_t)(n*T_ + t)*V_ + v)*64 + ck*8)*2);
        int byte = (col*128 + ck*16) ^ ((col & 7) << 4);
        *(float4*)((char*)slab + byte) = val;
    }
    __syncthreads();

    const int lane = tid & 63, wave = tid >> 6;
    const int l15 = lane & 15, lq = lane >> 4;
    const int colw = wave * 128;

    f32x4 acc[4][8] = {};
    bf16x8 aA[4], aB[4];
    LOADA(aA, 0);
    #pragma unroll 1
    for (int s = 0; s < 18; s += 2) {        // (kt, cb) flattened, pipelined
        LOADA(aB, s + 1);
        COMPUTE(aA, s);
        if (s + 2 < 18) LOADA(aA, s + 2);
        COMPUTE(aB, s + 1);
    }

    // epilogue: bias + store + per-block BN partials
    #pragma unroll
    for (int mt = 0; mt < 4; ++mt) {
        #pragma unroll
        for (int r = 0; r < 4; ++r) {
            const int o = mt*16 + lq*4 + r;
            const float bias = bt[o];
            float ls = 0.f, lsq = 0.f;
            #pragma unroll
            for (int nf = 0; nf < 8; ++nf) {
                int ocol = colw + nf*16 + l15;
                if (ocol < TCOLS) {
                    int tl = ocol / 25, v = ocol - 25*tl;
                    float val = acc[mt][nf][r] + bias;
                    y3[((size_t)(n*C_ + o)*T_ + t0 + tl)*V_ + v] = val;
                    ls += val; lsq += val*val;
                }
            }
            atomicAdd(&s_sum[o], ls);
            atomicAdd(&s_sq[o], lsq);
        }
    }
    __syncthreads();
    if (tid < 64) {
        psum[(size_t)tid*NBLK + blockIdx.x] = s_sum[tid];
        psq [(size_t)tid*NBLK + blockIdx.x] = s_sq [tid];
    }
}

// ---------------------------------------------------------------------------
// stats: reduce partials -> per-channel scale/shift
// ---------------------------------------------------------------------------
__global__ __launch_bounds__(256) void stats_kernel(
    const float* __restrict__ psum, const float* __restrict__ psq,
    const float* __restrict__ gamma, const float* __restrict__ beta,
    float* __restrict__ sb)
{
    const int o = blockIdx.x;
    const int tid = threadIdx.x;
    float s = 0.f, q = 0.f;
    for (int i = tid; i < NBLK; i += 256) {
        s += psum[(size_t)o*NBLK + i];
        q += psq [(size_t)o*NBLK + i];
    }
    __shared__ float rs[256], rq[256];
    rs[tid] = s; rq[tid] = q;
    __syncthreads();
    for (int off = 128; off > 0; off >>= 1) {
        if (tid < off) { rs[tid] += rs[tid + off]; rq[tid] += rq[tid + off]; }
        __syncthreads();
    }
    if (tid == 0) {
        const float cnt = (float)(N_ * T_ * V_);
        float mean = rs[0] / cnt;
        float var  = rq[0] / cnt - mean * mean;
        float rstd = rsqrtf(var + 1e-5f);
        float sc   = gamma[o] * rstd;
        sb[o]      = sc;
        sb[C_ + o] = beta[o] - mean * sc;
    }
}

// ---------------------------------------------------------------------------
// BN + residual + ReLU, in place on d_out
// ---------------------------------------------------------------------------
__global__ __launch_bounds__(256) void bn_res_relu_kernel(
    const float* __restrict__ x, const float* __restrict__ sb,
    float* __restrict__ y)
{
    const size_t total4 = (size_t)N_ * C_ * T_ * V_ / 4;  // 7,680,000
    size_t i4 = (size_t)blockIdx.x * 256 + threadIdx.x;
    if (i4 >= total4) return;
    const int c = (int)((i4 / (T_ * V_ / 4)) % C_);
    const float sc = sb[c], sh = sb[C_ + c];
    float4 yv = ((const float4*)y)[i4];
    float4 xv = ((const float4*)x)[i4];
    float4 o;
    o.x = fmaxf(yv.x * sc + sh + xv.x, 0.0f);
    o.y = fmaxf(yv.y * sc + sh + xv.y, 0.0f);
    o.z = fmaxf(yv.z * sc + sh + xv.z, 0.0f);
    o.w = fmaxf(yv.w * sc + sh + xv.w, 0.0f);
    ((float4*)y)[i4] = o;
}

// ---------------------------------------------------------------------------
extern "C" void kernel_launch(void* const* d_in, const int* in_sizes, int n_in,
                              void* d_out, int out_size, void* d_ws, size_t ws_size,
                              hipStream_t stream)
{
    const float* x     = (const float*)d_in[0];
    const float* A     = (const float*)d_in[1];
    const float* wg    = (const float*)d_in[2];
    const float* bg    = (const float*)d_in[3];
    const float* wt    = (const float*)d_in[4];
    const float* bt    = (const float*)d_in[5];
    const float* gamma = (const float*)d_in[6];
    const float* beta  = (const float*)d_in[7];
    float* out = (float*)d_out;

    char* wsb = (char*)d_ws;
    // y2: [(n,t,v)][c] bf16, 61,440,000 B
    unsigned short* y2   = (unsigned short*)wsb;
    float* psum          = (float*)(wsb + 61440000);
    float* psq           = (float*)(wsb + 61440000 + 245760);
    float* sb            = (float*)(wsb + 61440000 + 2*245760);
    unsigned short* Wtb  = (unsigned short*)(wsb + 61440000 + 2*245760 + 512);
    unsigned short* Wgbt = (unsigned short*)(wsb + 61440000 + 2*245760 + 512 + 73728);
    float* bias2         = (float*)(wsb + 61440000 + 2*245760 + 512 + 73728 + 24576);
    unsigned short* Abt  = (unsigned short*)(wsb + 61440000 + 2*245760 + 512 + 73728 + 24576 + 6400);

    prep_kernel<<<214, 256, 0, stream>>>(wt, wg, bg, A, Wtb, Wgbt, bias2, Abt);
    gcn_kernel<<<N_*GTILES, 256, 0, stream>>>(x, Wgbt, Abt, bias2, y2);
    tcn_kernel<<<NBLK, 256, 0, stream>>>(y2, Wtb, bt, out, psum, psq);
    stats_kernel<<<C_, 256, 0, stream>>>(psum, psq, gamma, beta, sb);
    const size_t total4 = (size_t)N_ * C_ * T_ * V_ / 4;
    bn_res_relu_kernel<<<(int)((total4 + 255) / 256), 256, 0, stream>>>(x, sb, out);
}

// Round 4
// 386.753 us; speedup vs baseline: 13.1672x; 1.0473x over previous
//
#include <hip/hip_runtime.h>
#include <hip/hip_bf16.h>

#define N_    64
#define C_    64      // C_in == C_out
#define T_    300
#define V_    25
#define K_    3
#define KT_   9
#define PAD_  4

typedef short bf16x8 __attribute__((ext_vector_type(8)));
typedef float f32x4  __attribute__((ext_vector_type(4)));

static __device__ __forceinline__ unsigned short f2bf(float f) {
    __hip_bfloat16 h = __float2bfloat16(f);
    return __builtin_bit_cast(unsigned short, h);
}
static __device__ __forceinline__ unsigned int pk2(float a, float b) {
    return (unsigned int)f2bf(a) | ((unsigned int)f2bf(b) << 16);
}
static __device__ __forceinline__ float bfhi(unsigned int u) {   // low bf16 -> f32
    return __builtin_bit_cast(float, u << 16);
}
static __device__ __forceinline__ float bflo(unsigned int u) {   // high bf16 -> f32
    return __builtin_bit_cast(float, u & 0xffff0000u);
}

// ---------------------------------------------------------------------------
// prep: weight tables (bf16, MFMA layouts) + fused GCN bias table.
//   Wtb   [kt][o][c]     = Wt[o][c][kt]                      (9*64*64)
//   Wgbt  [o][k*64+ci]   = Wg[k*64+o][ci]                    (64*192)
//   bias2b[w][c]         = bf16(sum_k bg[k*64+c]*colsumA)    (25*64)
//   Abt   [k][w:32][v:40]= A[k,v,w] zero-padded              (3*32*40)
// ---------------------------------------------------------------------------
__global__ __launch_bounds__(256) void prep_kernel(
    const float* __restrict__ Wt, const float* __restrict__ Wg,
    const float* __restrict__ bg, const float* __restrict__ A,
    unsigned short* __restrict__ Wtb, unsigned short* __restrict__ Wgbt,
    unsigned short* __restrict__ bias2b, unsigned short* __restrict__ Abt)
{
    int i = blockIdx.x * 256 + threadIdx.x;
    if (i < 9*64*64) {
        int kt = i >> 12, r = i & 4095, o = r >> 6, c = r & 63;
        Wtb[i] = f2bf(Wt[(size_t)(o*64 + c)*9 + kt]);
    }
    int j = i - 9*64*64;
    if (j >= 0 && j < 64*192) {
        int o = j / 192, kc = j - 192*(j/192);
        int k = kc >> 6, ci = kc & 63;
        Wgbt[j] = f2bf(Wg[(size_t)(k*64 + o)*64 + ci]);
    }
    int m = j - 64*192;
    if (m >= 0 && m < 64*25) {
        int c = m / 25, w = m - 25*(m/25);
        float s = 0.f;
        for (int k = 0; k < 3; ++k) {
            float col = 0.f;
            for (int v = 0; v < 25; ++v) col += A[k*625 + v*25 + w];
            s += bg[k*64 + c] * col;
        }
        bias2b[w*64 + c] = f2bf(s);
    }
    int p = m - 64*25;
    if (p >= 0 && p < 3*32*40) {
        int k = p / 1280, r = p - 1280*k, w = r / 40, v = r - 40*(r/40);
        float val = (w < 25 && v < 25) ? A[k*625 + v*25 + w] : 0.f;
        Abt[p] = f2bf(val);
    }
}

// ---------------------------------------------------------------------------
// GCN (all-MFMA, t-looped): per (n, 12-t group), 6 tiles of GTT=2.
//   stage1: xa[(tl,w)][k*64+ci] via MFMA (M=128, K=32pad, N=32pad) per k
//   stage2: y2[o][(tl,w)] via MFMA (M=64, K=192, N=64, 50 valid)
// Single xslab; next tile prefetched to regs, LDS-written after bar1.
// ---------------------------------------------------------------------------
#define GTT    2
#define GSUB   6
#define GGRP   (T_/(GTT*GSUB))   // 25
#define XROWS  (GTT*C_)          // 128
#define GCVAL  (GTT*V_)          // 50

__global__ __launch_bounds__(256, 3) void gcn_kernel(
    const float* __restrict__ x,
    const unsigned short* __restrict__ Wgbt,
    const unsigned short* __restrict__ Abt,
    const unsigned short* __restrict__ bias2b,
    unsigned short* __restrict__ y2)
{
    __shared__ unsigned short xslab[XROWS*40];   // 80B rows, 10240 B
    __shared__ unsigned short Ab[3*32*40];       // 7680 B
    __shared__ unsigned short xa[GCVAL*200];     // 400B rows, 20000 B
    __shared__ unsigned int   bias2L[25*34];     // 136B rows, 3400 B

    const int tid  = threadIdx.x;
    const int n    = blockIdx.x / GGRP;
    const int tg   = (blockIdx.x % GGRP) * (GTT*GSUB);
    const int lane = tid & 63, wave = tid >> 6;
    const int l15  = lane & 15, lq = lane >> 4;

    // persistent stage-2 weight frags, pinned against load-sinking
    bf16x8 wfrag[4][6];
    #pragma unroll
    for (int mt = 0; mt < 4; ++mt)
        #pragma unroll
        for (int cb = 0; cb < 6; ++cb) {
            wfrag[mt][cb] = *(const bf16x8*)(Wgbt + (mt*16 + l15)*192 + cb*32 + lq*8);
            asm volatile("" : "+v"(wfrag[mt][cb]));
        }

    for (int i = tid; i < 1920; i += 256)
        ((unsigned int*)Ab)[i] = ((const unsigned int*)Abt)[i];
    for (int i = tid; i < 800; i += 256)
        bias2L[(i >> 5)*34 + (i & 31)] = ((const unsigned int*)bias2b)[i];
    // zero K-pad (elems 26..31 = u32 slots 13..15 of 20)
    for (int i = tid; i < XROWS*3; i += 256) {
        int r = i / 3, z = i - 3*r;
        ((unsigned int*)xslab)[r*20 + 13 + z] = 0u;
    }
    // fill xslab with tile 0
    #pragma unroll
    for (int s7 = 0; s7 < 7; ++s7) {
        int slot = tid + s7*256;
        if (slot < XROWS*13) {
            int row = slot/13, sl = slot - 13*row;
            int ci = row & 63, tl = row >> 6;
            const float* xr = x + ((size_t)(n*C_ + ci)*T_ + tg + tl)*V_;
            float f0, f1;
            if (sl < 12) { float2 t2 = *(const float2*)(xr + 2*sl); f0 = t2.x; f1 = t2.y; }
            else         { f0 = xr[24]; f1 = 0.f; }
            ((unsigned int*)xslab)[row*20 + sl] = pk2(f0, f1);
        }
    }
    __syncthreads();

    for (int j = 0; j < GSUB; ++j) {
        const int tb = tg + j*GTT;
        // ---- prefetch next tile into regs (issues early, waits late)
        float2 Lr[7];
        const bool havenext = (j + 1 < GSUB);
        if (havenext) {
            #pragma unroll
            for (int s7 = 0; s7 < 7; ++s7) {
                int slot = tid + s7*256;
                if (slot < XROWS*13) {
                    int row = slot/13, sl = slot - 13*row;
                    int ci = row & 63, tl = row >> 6;
                    const float* xr = x + ((size_t)(n*C_ + ci)*T_ + tb + GTT + tl)*V_;
                    if (sl < 12) Lr[s7] = *(const float2*)(xr + 2*sl);
                    else         { Lr[s7].x = xr[24]; Lr[s7].y = 0.f; }
                }
            }
        }
        // ---- stage 1: x-slab @ A_k^T -> xa
        {
            const int mt0 = wave*2;
            bf16x8 xf0 = *(const bf16x8*)(xslab + (mt0*16 + l15)*40 + lq*8);
            bf16x8 xf1 = *(const bf16x8*)(xslab + ((mt0+1)*16 + l15)*40 + lq*8);
            #pragma unroll
            for (int k = 0; k < 3; ++k) {
                #pragma unroll
                for (int nt = 0; nt < 2; ++nt) {
                    bf16x8 bf = *(const bf16x8*)(Ab + (k*32 + nt*16 + l15)*40 + lq*8);
                    f32x4 d0 = {}, d1 = {};
                    d0 = __builtin_amdgcn_mfma_f32_16x16x32_bf16(xf0, bf, d0, 0, 0, 0);
                    d1 = __builtin_amdgcn_mfma_f32_16x16x32_bf16(xf1, bf, d1, 0, 0, 0);
                    const int w = nt*16 + l15;
                    if (w < 25) {
                        const int tl0 = mt0 >> 2, ci0 = (mt0 & 3)*16 + lq*4;
                        unsigned long long pv0 =
                              (unsigned long long)pk2(d0[0], d0[1])
                            | ((unsigned long long)pk2(d0[2], d0[3]) << 32);
                        *(unsigned long long*)((char*)xa + (tl0*25 + w)*400 + (k*64 + ci0)*2) = pv0;
                        const int mt1 = mt0 + 1;
                        const int tl1 = mt1 >> 2, ci1 = (mt1 & 3)*16 + lq*4;
                        unsigned long long pv1 =
                              (unsigned long long)pk2(d1[0], d1[1])
                            | ((unsigned long long)pk2(d1[2], d1[3]) << 32);
                        *(unsigned long long*)((char*)xa + (tl1*25 + w)*400 + (k*64 + ci1)*2) = pv1;
                    }
                }
            }
        }
        __syncthreads();   // xa ready; xslab readers done
        // ---- stage 2: Wgbt @ xa -> y2 (+bias from LDS)
        {
            const int col = wave*16 + l15;
            const int c3  = (col < GCVAL) ? col : (GCVAL - 1);
            f32x4 acc[4] = {};
            #pragma unroll
            for (int cb = 0; cb < 6; ++cb) {
                bf16x8 b = *(const bf16x8*)((const char*)xa + c3*400 + cb*64 + lq*16);
                #pragma unroll
                for (int mt = 0; mt < 4; ++mt)
                    acc[mt] = __builtin_amdgcn_mfma_f32_16x16x32_bf16(
                        wfrag[mt][cb], b, acc[mt], 0, 0, 0);
            }
            if (col < GCVAL) {
                const int tl = col / 25, w = col - 25*(col/25);
                const size_t gcol = ((size_t)n*T_ + tb + tl)*V_ + w;
                #pragma unroll
                for (int mt = 0; mt < 4; ++mt) {
                    const int o0 = mt*16 + lq*4;
                    unsigned int bu0 = bias2L[w*34 + (o0 >> 1)];
                    unsigned int bu1 = bias2L[w*34 + (o0 >> 1) + 1];
                    float v0 = acc[mt][0] + bfhi(bu0);
                    float v1 = acc[mt][1] + bflo(bu0);
                    float v2 = acc[mt][2] + bfhi(bu1);
                    float v3 = acc[mt][3] + bflo(bu1);
                    unsigned long long pv = (unsigned long long)pk2(v0, v1)
                                          | ((unsigned long long)pk2(v2, v3) << 32);
                    *(unsigned long long*)((char*)y2 + (gcol*64 + o0)*2) = pv;
                }
            }
        }
        // ---- write prefetched tile into xslab (overlaps stage-2 epilogue)
        if (havenext) {
            #pragma unroll
            for (int s7 = 0; s7 < 7; ++s7) {
                int slot = tid + s7*256;
                if (slot < XROWS*13) {
                    int row = slot/13, sl = slot - 13*row;
                    ((unsigned int*)xslab)[row*20 + sl] = pk2(Lr[s7].x, Lr[s7].y);
                }
            }
        }
        __syncthreads();   // xa consumed, xslab(next) visible
    }
}

// ---------------------------------------------------------------------------
// TCN: per (n, 20-t tile). K split into two 32-channel phases; slab 712x80B
// (2-way banks, 16B-aligned rows). Accumulators persist across phases.
// 9 conv taps = column-shifted MFMA reads. Fused bias + BN partials.
// ---------------------------------------------------------------------------
#define TTT    20
#define TCOLS  (TTT*25)         // 500
#define SLABC  712              // 500 + 200 halo + 12 overrun pad
#define TTILES (T_/TTT)         // 15
#define NBLK   (N_*TTILES)      // 960

#define TLOADA(dst, kt_) { \
    _Pragma("unroll") \
    for (int mt = 0; mt < 4; ++mt) \
        dst[mt] = *(const bf16x8*)(Wtb + (size_t)(kt_)*4096 + (mt*16 + l15)*64 \
                                   + h*32 + lq*8); }

#define TCOMP(a_, kt_) { \
    _Pragma("unroll") \
    for (int nf = 0; nf < 8; ++nf) { \
        int col = colw + nf*16 + l15 + (kt_)*25; \
        bf16x8 b = *(const bf16x8*)((const char*)slab + col*80 + lq*16); \
        _Pragma("unroll") \
        for (int mt = 0; mt < 4; ++mt) \
            acc[mt][nf] = __builtin_amdgcn_mfma_f32_16x16x32_bf16( \
                a_[mt], b, acc[mt][nf], 0, 0, 0); } }

__global__ __launch_bounds__(256, 2) void tcn_kernel(
    const unsigned short* __restrict__ y2, const unsigned short* __restrict__ Wtb,
    const float* __restrict__ bt,
    float* __restrict__ y3, float* __restrict__ psum, float* __restrict__ psq)
{
    __shared__ unsigned short slab[SLABC*40];   // 56960 B
    __shared__ float s_sum[64], s_sq[64];

    const int tid = threadIdx.x;
    const int n  = blockIdx.x / TTILES;
    const int t0 = (blockIdx.x % TTILES) * TTT;
    const int lane = tid & 63, wave = tid >> 6;
    const int l15 = lane & 15, lq = lane >> 4;
    const int colw = wave * 128;

    if (tid < 64) { s_sum[tid] = 0.f; s_sq[tid] = 0.f; }

    f32x4 acc[4][8] = {};

    #pragma unroll
    for (int h = 0; h < 2; ++h) {
        __syncthreads();    // protect slab overwrite vs previous phase readers
        for (int i = tid; i < SLABC*4; i += 256) {
            int col = i >> 2, ck = i & 3;
            int tl = col / 25, v = col - 25*tl;
            int t = t0 - PAD_ + tl;
            float4 val = {0.f, 0.f, 0.f, 0.f};
            if (t >= 0 && t < T_)
                val = *(const float4*)(y2 + (((size_t)(n*T_ + t)*V_ + v)*64 + h*32 + ck*8));
            *(float4*)((char*)slab + col*80 + ck*16) = val;
        }
        __syncthreads();
        bf16x8 aA[4], aB[4];
        TLOADA(aA, 0);
        #pragma unroll
        for (int kt = 0; kt < 9; ++kt) {
            if ((kt & 1) == 0) {
                if (kt < 8) TLOADA(aB, kt + 1);
                TCOMP(aA, kt);
            } else {
                if (kt < 8) TLOADA(aA, kt + 1);
                TCOMP(aB, kt);
            }
        }
    }

    // epilogue: bias + store + per-block BN partials
    #pragma unroll
    for (int mt = 0; mt < 4; ++mt) {
        #pragma unroll
        for (int r = 0; r < 4; ++r) {
            const int o = mt*16 + lq*4 + r;
            const float bias = bt[o];
            float ls = 0.f, lsq = 0.f;
            #pragma unroll
            for (int nf = 0; nf < 8; ++nf) {
                int ocol = colw + nf*16 + l15;
                if (ocol < TCOLS) {
                    int tl = ocol / 25, v = ocol - 25*tl;
                    float val = acc[mt][nf][r] + bias;
                    y3[((size_t)(n*C_ + o)*T_ + t0 + tl)*V_ + v] = val;
                    ls += val; lsq += val*val;
                }
            }
            atomicAdd(&s_sum[o], ls);
            atomicAdd(&s_sq[o], lsq);
        }
    }
    __syncthreads();
    if (tid < 64) {
        psum[(size_t)tid*NBLK + blockIdx.x] = s_sum[tid];
        psq [(size_t)tid*NBLK + blockIdx.x] = s_sq [tid];
    }
}

// ---------------------------------------------------------------------------
// stats: reduce partials -> per-channel scale/shift
// ---------------------------------------------------------------------------
__global__ __launch_bounds__(256) void stats_kernel(
    const float* __restrict__ psum, const float* __restrict__ psq,
    const float* __restrict__ gamma, const float* __restrict__ beta,
    float* __restrict__ sb)
{
    const int o = blockIdx.x;
    const int tid = threadIdx.x;
    float s = 0.f, q = 0.f;
    for (int i = tid; i < NBLK; i += 256) {
        s += psum[(size_t)o*NBLK + i];
        q += psq [(size_t)o*NBLK + i];
    }
    __shared__ float rs[256], rq[256];
    rs[tid] = s; rq[tid] = q;
    __syncthreads();
    for (int off = 128; off > 0; off >>= 1) {
        if (tid < off) { rs[tid] += rs[tid + off]; rq[tid] += rq[tid + off]; }
        __syncthreads();
    }
    if (tid == 0) {
        const float cnt = (float)(N_ * T_ * V_);
        float mean = rs[0] / cnt;
        float var  = rq[0] / cnt - mean * mean;
        float rstd = rsqrtf(var + 1e-5f);
        float sc   = gamma[o] * rstd;
        sb[o]      = sc;
        sb[C_ + o] = beta[o] - mean * sc;
    }
}

// ---------------------------------------------------------------------------
// BN + residual + ReLU, in place on d_out
// ---------------------------------------------------------------------------
__global__ __launch_bounds__(256) void bn_res_relu_kernel(
    const float* __restrict__ x, const float* __restrict__ sb,
    float* __restrict__ y)
{
    const size_t total4 = (size_t)N_ * C_ * T_ * V_ / 4;  // 7,680,000
    size_t i4 = (size_t)blockIdx.x * 256 + threadIdx.x;
    if (i4 >= total4) return;
    const int c = (int)((i4 / (T_ * V_ / 4)) % C_);
    const float sc = sb[c], sh = sb[C_ + c];
    float4 yv = ((const float4*)y)[i4];
    float4 xv = ((const float4*)x)[i4];
    float4 o;
    o.x = fmaxf(yv.x * sc + sh + xv.x, 0.0f);
    o.y = fmaxf(yv.y * sc + sh + xv.y, 0.0f);
    o.z = fmaxf(yv.z * sc + sh + xv.z, 0.0f);
    o.w = fmaxf(yv.w * sc + sh + xv.w, 0.0f);
    ((float4*)y)[i4] = o;
}

// ---------------------------------------------------------------------------
extern "C" void kernel_launch(void* const* d_in, const int* in_sizes, int n_in,
                              void* d_out, int out_size, void* d_ws, size_t ws_size,
                              hipStream_t stream)
{
    const float* x     = (const float*)d_in[0];
    const float* A     = (const float*)d_in[1];
    const float* wg    = (const float*)d_in[2];
    const float* bg    = (const float*)d_in[3];
    const float* wt    = (const float*)d_in[4];
    const float* bt    = (const float*)d_in[5];
    const float* gamma = (const float*)d_in[6];
    const float* beta  = (const float*)d_in[7];
    float* out = (float*)d_out;

    char* wsb = (char*)d_ws;
    unsigned short* y2     = (unsigned short*)wsb;                    // 61,440,000 B
    float* psum            = (float*)(wsb + 61440000);                // 245,760
    float* psq             = (float*)(wsb + 61685760);                // 245,760
    float* sb              = (float*)(wsb + 61931520);                // 512
    unsigned short* Wtb    = (unsigned short*)(wsb + 61932032);       // 73,728
    unsigned short* Wgbt   = (unsigned short*)(wsb + 62005760);       // 24,576
    unsigned short* bias2b = (unsigned short*)(wsb + 62030336);       // 3,200
    unsigned short* Abt    = (unsigned short*)(wsb + 62033536);       // 7,680

    prep_kernel<<<214, 256, 0, stream>>>(wt, wg, bg, A, Wtb, Wgbt, bias2b, Abt);
    gcn_kernel<<<N_*GGRP, 256, 0, stream>>>(x, Wgbt, Abt, bias2b, y2);
    tcn_kernel<<<NBLK, 256, 0, stream>>>(y2, Wtb, bt, out, psum, psq);
    stats_kernel<<<C_, 256, 0, stream>>>(psum, psq, gamma, beta, sb);
    const size_t total4 = (size_t)N_ * C_ * T_ * V_ / 4;
    bn_res_relu_kernel<<<(int)((total4 + 255) / 256), 256, 0, stream>>>(x, sb, out);
}

// Round 5
// 266.581 us; speedup vs baseline: 19.1029x; 1.4508x over previous
//
#include <hip/hip_runtime.h>
#include <hip/hip_bf16.h>

#define N_    64
#define C_    64      // C_in == C_out
#define T_    300
#define V_    25
#define K_    3
#define KT_   9
#define PAD_  4

typedef short bf16x8 __attribute__((ext_vector_type(8)));
typedef float f32x4  __attribute__((ext_vector_type(4)));

static __device__ __forceinline__ unsigned short f2bf(float f) {
    __hip_bfloat16 h = __float2bfloat16(f);
    return __builtin_bit_cast(unsigned short, h);
}
static __device__ __forceinline__ unsigned int pk2(float a, float b) {
    return (unsigned int)f2bf(a) | ((unsigned int)f2bf(b) << 16);
}
static __device__ __forceinline__ float bfhi(unsigned int u) {   // low bf16 -> f32
    return __builtin_bit_cast(float, u << 16);
}
static __device__ __forceinline__ float bflo(unsigned int u) {   // high bf16 -> f32
    return __builtin_bit_cast(float, u & 0xffff0000u);
}
static __device__ __forceinline__ float bf2f(unsigned short u) {
    return __builtin_bit_cast(float, (unsigned int)u << 16);
}

// ---------------------------------------------------------------------------
// prep: weight tables (bf16, MFMA layouts) + fused GCN bias table.
//   Wtb   [kt][o][c]     = Wt[o][c][kt]                      (9*64*64)
//   Wgbt  [o][k*64+ci]   = Wg[k*64+o][ci]                    (64*192)
//   bias2b[w][c]         = bf16(sum_k bg[k*64+c]*colsumA)    (25*64)
//   Abt   [k][w:32][v:40]= A[k,v,w] zero-padded              (3*32*40)
// ---------------------------------------------------------------------------
__global__ __launch_bounds__(256) void prep_kernel(
    const float* __restrict__ Wt, const float* __restrict__ Wg,
    const float* __restrict__ bg, const float* __restrict__ A,
    unsigned short* __restrict__ Wtb, unsigned short* __restrict__ Wgbt,
    unsigned short* __restrict__ bias2b, unsigned short* __restrict__ Abt)
{
    int i = blockIdx.x * 256 + threadIdx.x;
    if (i < 9*64*64) {
        int kt = i >> 12, r = i & 4095, o = r >> 6, c = r & 63;
        Wtb[i] = f2bf(Wt[(size_t)(o*64 + c)*9 + kt]);
    }
    int j = i - 9*64*64;
    if (j >= 0 && j < 64*192) {
        int o = j / 192, kc = j - 192*(j/192);
        int k = kc >> 6, ci = kc & 63;
        Wgbt[j] = f2bf(Wg[(size_t)(k*64 + o)*64 + ci]);
    }
    int m = j - 64*192;
    if (m >= 0 && m < 64*25) {
        int c = m / 25, w = m - 25*(m/25);
        float s = 0.f;
        for (int k = 0; k < 3; ++k) {
            float col = 0.f;
            for (int v = 0; v < 25; ++v) col += A[k*625 + v*25 + w];
            s += bg[k*64 + c] * col;
        }
        bias2b[w*64 + c] = f2bf(s);
    }
    int p = m - 64*25;
    if (p >= 0 && p < 3*32*40) {
        int k = p / 1280, r = p - 1280*k, w = r / 40, v = r - 40*(r/40);
        float val = (w < 25 && v < 25) ? A[k*625 + v*25 + w] : 0.f;
        Abt[p] = f2bf(val);
    }
}

// ---------------------------------------------------------------------------
// GCN: grid 1280 = 5 blocks/CU, all co-resident. Wave owns M (o / ci block).
//  per t: stage1 (6 MFMA/wave)  x[ci][v] @ A_k^T[v][w] -> xa[w][k*64+ci]
//         stage2 (12 MFMA/wave) Wgbt[o][kc] @ xa[col][kc] -> y2[(n,t,w)][o]
//  wfrag/afrag pinned in VGPRs (48 regs), x(t+1) prefetched to regs.
// ---------------------------------------------------------------------------
#define GSUB   15
#define GGRP   (T_/GSUB)     // 20
#define NGBLK  (N_*GGRP)     // 1280

__global__ __launch_bounds__(256, 5) void gcn_kernel(
    const float* __restrict__ x,
    const unsigned short* __restrict__ Wgbt,
    const unsigned short* __restrict__ Abt,
    const unsigned short* __restrict__ bias2b,
    unsigned short* __restrict__ y2)
{
    __shared__ unsigned short xslab[64*40];    // [ci][40e]  80B rows, 5120 B
    __shared__ unsigned short xa[32*200];      // [w][200e] 400B rows, 12800 B
    __shared__ unsigned int   bias2L[25*34];   // [w][34 u32] 136B rows, 3400 B

    const int tid  = threadIdx.x;
    const int n    = blockIdx.x / GGRP;
    const int tg   = (blockIdx.x % GGRP) * GSUB;
    const int lane = tid & 63, wave = tid >> 6;
    const int l15  = lane & 15, lq = lane >> 4;

    // pinned weight frags: 6 stage-2 (o rows = wave*16+l15) + 6 stage-1 A-frags
    bf16x8 wfrag[6], afrag[6];
    #pragma unroll
    for (int cb = 0; cb < 6; ++cb) {
        wfrag[cb] = *(const bf16x8*)(Wgbt + (wave*16 + l15)*192 + cb*32 + lq*8);
        asm volatile("" : "+v"(wfrag[cb]));
    }
    #pragma unroll
    for (int s = 0; s < 6; ++s) {   // s = k*2 + nt
        afrag[s] = *(const bf16x8*)(Abt + ((s >> 1)*32 + (s & 1)*16 + l15)*40 + lq*8);
        asm volatile("" : "+v"(afrag[s]));
    }

    for (int i = tid; i < 800; i += 256)
        bias2L[(i >> 5)*34 + (i & 31)] = ((const unsigned int*)bias2b)[i];
    // zero K-pad (elems 26..31 = u32 slots 13..15; persists all iterations)
    if (tid < 192) {
        int r = tid / 3, z = tid - 3*(tid/3);
        ((unsigned int*)xslab)[r*20 + 13 + z] = 0u;
    }
    // fill xslab with t = tg  (64 rows x 13 u32 slots = 832)
    #pragma unroll
    for (int s = 0; s < 4; ++s) {
        int slot = tid + s*256;
        if (slot < 64*13) {
            int row = slot/13, sl = slot - 13*row;
            const float* xr = x + ((size_t)(n*C_ + row)*T_ + tg)*V_;
            float f0, f1;
            if (sl < 12) { float2 t2 = *(const float2*)(xr + 2*sl); f0 = t2.x; f1 = t2.y; }
            else         { f0 = xr[24]; f1 = 0.f; }
            ((unsigned int*)xslab)[row*20 + sl] = pk2(f0, f1);
        }
    }
    __syncthreads();

    for (int j = 0; j < GSUB; ++j) {
        const int t = tg + j;
        // ---- prefetch x(t+1) into regs
        float2 Lr[4];
        const bool hn = (j + 1 < GSUB);
        if (hn) {
            #pragma unroll
            for (int s = 0; s < 4; ++s) {
                int slot = tid + s*256;
                if (slot < 64*13) {
                    int row = slot/13, sl = slot - 13*row;
                    const float* xr = x + ((size_t)(n*C_ + row)*T_ + t + 1)*V_;
                    if (sl < 12) Lr[s] = *(const float2*)(xr + 2*sl);
                    else         { Lr[s].x = xr[24]; Lr[s].y = 0.f; }
                }
            }
        }
        // ---- stage 1: xa[w][k*64+ci] (wave owns ci-block = wave*16..+15)
        {
            bf16x8 xf = *(const bf16x8*)(xslab + (wave*16 + l15)*40 + lq*8);
            #pragma unroll
            for (int s = 0; s < 6; ++s) {
                f32x4 d = {};
                d = __builtin_amdgcn_mfma_f32_16x16x32_bf16(xf, afrag[s], d, 0, 0, 0);
                const int w = (s & 1)*16 + l15;
                if (w < 25) {
                    const int k = s >> 1;
                    unsigned long long pv = (unsigned long long)pk2(d[0], d[1])
                                          | ((unsigned long long)pk2(d[2], d[3]) << 32);
                    *(unsigned long long*)((char*)xa + w*400 + k*128 + wave*32 + lq*8) = pv;
                }
            }
        }
        __syncthreads();   // xa ready; xslab readers done
        // ---- stage 2: y2[(n,t,col)][o] (wave owns o-block = wave*16..+15)
        {
            f32x4 acc0 = {}, acc1 = {};
            #pragma unroll
            for (int cb = 0; cb < 6; ++cb) {
                bf16x8 b0 = *(const bf16x8*)((const char*)xa + l15*400      + cb*64 + lq*16);
                bf16x8 b1 = *(const bf16x8*)((const char*)xa + (16+l15)*400 + cb*64 + lq*16);
                acc0 = __builtin_amdgcn_mfma_f32_16x16x32_bf16(wfrag[cb], b0, acc0, 0, 0, 0);
                acc1 = __builtin_amdgcn_mfma_f32_16x16x32_bf16(wfrag[cb], b1, acc1, 0, 0, 0);
            }
            const int o0 = wave*16 + lq*4;
            {
                const int col = l15;                       // < 25 always
                unsigned int bu0 = bias2L[col*34 + (o0 >> 1)];
                unsigned int bu1 = bias2L[col*34 + (o0 >> 1) + 1];
                float v0 = acc0[0] + bfhi(bu0), v1 = acc0[1] + bflo(bu0);
                float v2 = acc0[2] + bfhi(bu1), v3 = acc0[3] + bflo(bu1);
                const size_t gcol = ((size_t)n*T_ + t)*V_ + col;
                *(unsigned long long*)(y2 + gcol*64 + o0) =
                      (unsigned long long)pk2(v0, v1)
                    | ((unsigned long long)pk2(v2, v3) << 32);
            }
            if (l15 < 9) {
                const int col = 16 + l15;
                unsigned int bu0 = bias2L[col*34 + (o0 >> 1)];
                unsigned int bu1 = bias2L[col*34 + (o0 >> 1) + 1];
                float v0 = acc1[0] + bfhi(bu0), v1 = acc1[1] + bflo(bu0);
                float v2 = acc1[2] + bfhi(bu1), v3 = acc1[3] + bflo(bu1);
                const size_t gcol = ((size_t)n*T_ + t)*V_ + col;
                *(unsigned long long*)(y2 + gcol*64 + o0) =
                      (unsigned long long)pk2(v0, v1)
                    | ((unsigned long long)pk2(v2, v3) << 32);
            }
        }
        // ---- write prefetched x(t+1) into xslab (xslab free after bar B)
        if (hn) {
            #pragma unroll
            for (int s = 0; s < 4; ++s) {
                int slot = tid + s*256;
                if (slot < 64*13) {
                    int row = slot/13, sl = slot - 13*row;
                    ((unsigned int*)xslab)[row*20 + sl] = pk2(Lr[s].x, Lr[s].y);
                }
            }
        }
        __syncthreads();   // xa consumed, xslab(t+1) visible
    }
}

// ---------------------------------------------------------------------------
// TCN: per (n, 20-t tile). K split into two 32-channel phases; slab 712x80B.
// 9 conv taps = column-shifted MFMA reads. Fused bias + BN partials.
// y3 stored bf16 (BF=1, in ws) or f32 (BF=0, in d_out).
// ---------------------------------------------------------------------------
#define TTT    20
#define TCOLS  (TTT*25)         // 500
#define SLABC  712              // 500 + 200 halo + 12 overrun pad
#define TTILES (T_/TTT)         // 15
#define NBLK   (N_*TTILES)      // 960

#define TLOADA(dst, kt_) { \
    _Pragma("unroll") \
    for (int mt = 0; mt < 4; ++mt) \
        dst[mt] = *(const bf16x8*)(Wtb + (size_t)(kt_)*4096 + (mt*16 + l15)*64 \
                                   + h*32 + lq*8); }

#define TCOMP(a_, kt_) { \
    _Pragma("unroll") \
    for (int nf = 0; nf < 8; ++nf) { \
        int col = colw + nf*16 + l15 + (kt_)*25; \
        bf16x8 b = *(const bf16x8*)((const char*)slab + col*80 + lq*16); \
        _Pragma("unroll") \
        for (int mt = 0; mt < 4; ++mt) \
            acc[mt][nf] = __builtin_amdgcn_mfma_f32_16x16x32_bf16( \
                a_[mt], b, acc[mt][nf], 0, 0, 0); } }

template<int BF>
__global__ __launch_bounds__(256, 2) void tcn_kernel(
    const unsigned short* __restrict__ y2, const unsigned short* __restrict__ Wtb,
    const float* __restrict__ bt,
    unsigned short* __restrict__ y3b, float* __restrict__ y3f,
    float* __restrict__ psum, float* __restrict__ psq)
{
    __shared__ unsigned short slab[SLABC*40];   // 56960 B
    __shared__ float s_sum[64], s_sq[64];

    const int tid = threadIdx.x;
    const int n  = blockIdx.x / TTILES;
    const int t0 = (blockIdx.x % TTILES) * TTT;
    const int lane = tid & 63, wave = tid >> 6;
    const int l15 = lane & 15, lq = lane >> 4;
    const int colw = wave * 128;

    if (tid < 64) { s_sum[tid] = 0.f; s_sq[tid] = 0.f; }

    f32x4 acc[4][8] = {};

    #pragma unroll
    for (int h = 0; h < 2; ++h) {
        __syncthreads();
        for (int i = tid; i < SLABC*4; i += 256) {
            int col = i >> 2, ck = i & 3;
            int tl = col / 25, v = col - 25*tl;
            int t = t0 - PAD_ + tl;
            float4 val = {0.f, 0.f, 0.f, 0.f};
            if (t >= 0 && t < T_)
                val = *(const float4*)(y2 + (((size_t)(n*T_ + t)*V_ + v)*64 + h*32 + ck*8));
            *(float4*)((char*)slab + col*80 + ck*16) = val;
        }
        __syncthreads();
        bf16x8 aA[4], aB[4];
        TLOADA(aA, 0);
        #pragma unroll
        for (int kt = 0; kt < 9; ++kt) {
            if ((kt & 1) == 0) {
                if (kt < 8) TLOADA(aB, kt + 1);
                TCOMP(aA, kt);
            } else {
                if (kt < 8) TLOADA(aA, kt + 1);
                TCOMP(aB, kt);
            }
        }
    }

    // epilogue: bias + store + per-block BN partials
    #pragma unroll
    for (int mt = 0; mt < 4; ++mt) {
        #pragma unroll
        for (int r = 0; r < 4; ++r) {
            const int o = mt*16 + lq*4 + r;
            const float bias = bt[o];
            float ls = 0.f, lsq = 0.f;
            #pragma unroll
            for (int nf = 0; nf < 8; ++nf) {
                int ocol = colw + nf*16 + l15;
                if (ocol < TCOLS) {
                    int tl = ocol / 25, v = ocol - 25*tl;
                    float val = acc[mt][nf][r] + bias;
                    size_t idx = ((size_t)(n*C_ + o)*T_ + t0 + tl)*V_ + v;
                    if (BF) y3b[idx] = f2bf(val);
                    else    y3f[idx] = val;
                    ls += val; lsq += val*val;
                }
            }
            atomicAdd(&s_sum[o], ls);
            atomicAdd(&s_sq[o], lsq);
        }
    }
    __syncthreads();
    if (tid < 64) {
        psum[(size_t)tid*NBLK + blockIdx.x] = s_sum[tid];
        psq [(size_t)tid*NBLK + blockIdx.x] = s_sq [tid];
    }
}

// ---------------------------------------------------------------------------
// stats: reduce partials -> per-channel scale/shift
// ---------------------------------------------------------------------------
__global__ __launch_bounds__(256) void stats_kernel(
    const float* __restrict__ psum, const float* __restrict__ psq,
    const float* __restrict__ gamma, const float* __restrict__ beta,
    float* __restrict__ sb)
{
    const int o = blockIdx.x;
    const int tid = threadIdx.x;
    float s = 0.f, q = 0.f;
    for (int i = tid; i < NBLK; i += 256) {
        s += psum[(size_t)o*NBLK + i];
        q += psq [(size_t)o*NBLK + i];
    }
    __shared__ float rs[256], rq[256];
    rs[tid] = s; rq[tid] = q;
    __syncthreads();
    for (int off = 128; off > 0; off >>= 1) {
        if (tid < off) { rs[tid] += rs[tid + off]; rq[tid] += rq[tid + off]; }
        __syncthreads();
    }
    if (tid == 0) {
        const float cnt = (float)(N_ * T_ * V_);
        float mean = rs[0] / cnt;
        float var  = rq[0] / cnt - mean * mean;
        float rstd = rsqrtf(var + 1e-5f);
        float sc   = gamma[o] * rstd;
        sb[o]      = sc;
        sb[C_ + o] = beta[o] - mean * sc;
    }
}

// ---------------------------------------------------------------------------
// BN + residual + ReLU
// ---------------------------------------------------------------------------
__global__ __launch_bounds__(256) void bn_res_relu_bf16_kernel(
    const float* __restrict__ x, const unsigned short* __restrict__ y3b,
    const float* __restrict__ sb, float* __restrict__ out)
{
    const size_t total4 = (size_t)N_ * C_ * T_ * V_ / 4;  // 7,680,000
    size_t i4 = (size_t)blockIdx.x * 256 + threadIdx.x;
    if (i4 >= total4) return;
    const int c = (int)((i4 / (T_ * V_ / 4)) % C_);
    const float sc = sb[c], sh = sb[C_ + c];
    ushort4 yv = ((const ushort4*)y3b)[i4];
    float4 xv = ((const float4*)x)[i4];
    float4 o;
    o.x = fmaxf(bf2f(yv.x) * sc + sh + xv.x, 0.0f);
    o.y = fmaxf(bf2f(yv.y) * sc + sh + xv.y, 0.0f);
    o.z = fmaxf(bf2f(yv.z) * sc + sh + xv.z, 0.0f);
    o.w = fmaxf(bf2f(yv.w) * sc + sh + xv.w, 0.0f);
    ((float4*)out)[i4] = o;
}

__global__ __launch_bounds__(256) void bn_res_relu_f32_kernel(
    const float* __restrict__ x, const float* __restrict__ sb,
    float* __restrict__ y)
{
    const size_t total4 = (size_t)N_ * C_ * T_ * V_ / 4;
    size_t i4 = (size_t)blockIdx.x * 256 + threadIdx.x;
    if (i4 >= total4) return;
    const int c = (int)((i4 / (T_ * V_ / 4)) % C_);
    const float sc = sb[c], sh = sb[C_ + c];
    float4 yv = ((const float4*)y)[i4];
    float4 xv = ((const float4*)x)[i4];
    float4 o;
    o.x = fmaxf(yv.x * sc + sh + xv.x, 0.0f);
    o.y = fmaxf(yv.y * sc + sh + xv.y, 0.0f);
    o.z = fmaxf(yv.z * sc + sh + xv.z, 0.0f);
    o.w = fmaxf(yv.w * sc + sh + xv.w, 0.0f);
    ((float4*)y)[i4] = o;
}

// ---------------------------------------------------------------------------
extern "C" void kernel_launch(void* const* d_in, const int* in_sizes, int n_in,
                              void* d_out, int out_size, void* d_ws, size_t ws_size,
                              hipStream_t stream)
{
    const float* x     = (const float*)d_in[0];
    const float* A     = (const float*)d_in[1];
    const float* wg    = (const float*)d_in[2];
    const float* bg    = (const float*)d_in[3];
    const float* wt    = (const float*)d_in[4];
    const float* bt    = (const float*)d_in[5];
    const float* gamma = (const float*)d_in[6];
    const float* beta  = (const float*)d_in[7];
    float* out = (float*)d_out;

    char* wsb = (char*)d_ws;
    const size_t Y2B   = 61440000;                 // y2 bf16
    const size_t Y3B   = 61440000;                 // y3 bf16 (optional)
    const size_t TABLE = 2*245760 + 512 + 73728 + 24576 + 3200 + 7680;
    const bool usebf = ws_size >= Y2B + Y3B + TABLE;

    unsigned short* y2  = (unsigned short*)wsb;
    unsigned short* y3b = (unsigned short*)(wsb + Y2B);
    const size_t base2  = usebf ? (Y2B + Y3B) : Y2B;
    float* psum            = (float*)(wsb + base2);
    float* psq             = (float*)(wsb + base2 + 245760);
    float* sb              = (float*)(wsb + base2 + 2*245760);
    unsigned short* Wtb    = (unsigned short*)(wsb + base2 + 2*245760 + 512);
    unsigned short* Wgbt   = (unsigned short*)(wsb + base2 + 2*245760 + 512 + 73728);
    unsigned short* bias2b = (unsigned short*)(wsb + base2 + 2*245760 + 512 + 73728 + 24576);
    unsigned short* Abt    = (unsigned short*)(wsb + base2 + 2*245760 + 512 + 73728 + 24576 + 3200);

    prep_kernel<<<214, 256, 0, stream>>>(wt, wg, bg, A, Wtb, Wgbt, bias2b, Abt);
    gcn_kernel<<<NGBLK, 256, 0, stream>>>(x, Wgbt, Abt, bias2b, y2);
    if (usebf)
        tcn_kernel<1><<<NBLK, 256, 0, stream>>>(y2, Wtb, bt, y3b, out, psum, psq);
    else
        tcn_kernel<0><<<NBLK, 256, 0, stream>>>(y2, Wtb, bt, y3b, out, psum, psq);
    stats_kernel<<<C_, 256, 0, stream>>>(psum, psq, gamma, beta, sb);
    const size_t total4 = (size_t)N_ * C_ * T_ * V_ / 4;
    const int bnblk = (int)((total4 + 255) / 256);
    if (usebf)
        bn_res_relu_bf16_kernel<<<bnblk, 256, 0, stream>>>(x, y3b, sb, out);
    else
        bn_res_relu_f32_kernel<<<bnblk, 256, 0, stream>>>(x, sb, out);
}